// Round 1
// baseline (1010.211 us; speedup 1.0000x reference)
//
#include <hip/hip_runtime.h>
#include <hip/hip_bf16.h>

#define NN 512
#define DEG 8
#define FD 128
#define HD 256
#define MD 256
#define OD 64
#define PD 2
#define HIST 10
#define TOTAL (10 * NN)       /* 5120 queue entries processed */
#define NPAR 648              /* entries with children: i < (TOTAL-S)/8 <= 632 */
#define INV_SQRT_H 0.0625f

typedef __hip_bfloat16 bf16;

// bit-level finite guard (fast-math-proof)
__device__ __forceinline__ float finz(float x) {
  unsigned u = __float_as_uint(x);
  return (((u >> 23) & 0xFFu) == 0xFFu) ? 0.f : x;
}

// runtime-dtype load: bf=1 -> bf16 array, bf=0 -> float array
__device__ __forceinline__ float ldin(const void* p, int idx, int bf) {
  if (bf) return __bfloat162float(((const bf16*)p)[idx]);
  return ((const float*)p)[idx];
}

// ---- static device scratch ----
__device__ float g_hist[NN * HIST * HD];    // ring buffers, 5.24 MB
__device__ float g_msgb[NPAR * MD];         // messages of entries with children
__device__ float g_WQK[HD * HD];            // Wq @ Wk^T   (kq = msg.WQK + ck)
__device__ float g_WrS[HD * HD];            // sum of 4 Wr row-blocks
__device__ float g_vq[HD];                  // Wq @ bk
__device__ float g_ck[HD];                  // Wk @ bq
__device__ float g_bqk;                     // bq . bk
__device__ int   g_node[TOTAL];
__device__ int   g_rank[TOTAL];
__device__ int   g_np[TOTAL];               // prev same-node occurrence (-1 none)
__device__ int   g_counts[NN];
__device__ int   g_done[TOTAL];             // dataflow completion flags
__device__ int   g_dtype;                   // 1 = float tensors are bf16
__device__ int   g_i64;                     // 1 = neighbors int64

__device__ __forceinline__ int decode_S(const int* dS) {
  int r = dS[0];
  if (r >= 1 && r <= NN) return r;
  float f = __int_as_float(r);
  if (f >= 1.f && f <= (float)NN) return (int)f;
  unsigned u = ((unsigned)r & 0xFFFFu) << 16;
  float g = __uint_as_float(u);
  if (g >= 1.f && g <= (float)NN) return (int)g;
  return 64;
}

__device__ __forceinline__ int get_nbr(const int* nbrs, int i64, int n, int d) {
  int v = i64 ? nbrs[2 * (n * DEG + d)] : nbrs[n * DEG + d];
  return (v < 0) ? 0 : (v >= NN ? NN - 1 : v);
}

// ---------------- phase A: dtype detect + BFS queue expansion (1 block) ----------------
__global__ void __launch_bounds__(1024)
k_bfs(const unsigned* __restrict__ xa_w, const int* __restrict__ nbrs,
      const int* __restrict__ dS) {
  __shared__ int s_node[TOTAL];              // 20 KB
  __shared__ int s_flags[1];
  const int t = threadIdx.x;
  if (t == 0) {                              // dtype + index-width detection (validated r6)
    int cnt = 0;
    for (int w = 0; w < 64; ++w) {
      unsigned lo = xa_w[w] & 0xFFFFu;
      float av = fabsf(__uint_as_float(lo << 16));
      if (av > 0.000244140625f && av < 64.f) ++cnt;
    }
    g_dtype = (cnt >= 32) ? 1 : 0;
    int allz = 1;
    for (int w = 1; w < 16; w += 2) allz &= (nbrs[w] == 0);
    g_i64 = allz;
    s_flags[0] = allz;
  }
  __syncthreads();
  const int i64 = s_flags[0];
  const int S = decode_S(dS);
  for (int i = t; i < S; i += 1024) s_node[i] = i;
  __syncthreads();
  int done = S;
  while (done < TOTAL) {                     // message tree, depth ~4
    long long nd = (long long)S + 8LL * (long long)done;
    int new_done = nd > (long long)TOTAL ? TOTAL : (int)nd;
    for (int i = done + t; i < new_done; i += 1024)
      s_node[i] = get_nbr(nbrs, i64, s_node[(i - S) >> 3], (i - S) & 7);
    __syncthreads();
    done = new_done;
  }
  for (int i = t; i < TOTAL; i += 1024) g_node[i] = s_node[i];
}

// ---------------- phase B: rank + prev-occurrence, ballot-parallel (512 blocks x 64) ----
// also zeroes the dataflow done-flags (TOTAL == NN*HIST slots, 10 per block)
__global__ void __launch_bounds__(64)
k_rank() {
  const int n = blockIdx.x;                  // node id
  const int l = threadIdx.x;                 // lane
  if (l < HIST) g_done[n * HIST + l] = 0;
  int k = 0, last = -1;
  for (int base = 0; base < TOTAL; base += 64) {
    int nd = g_node[base + l];
    unsigned long long m = __ballot(nd == n);
    if (nd == n) {
      unsigned long long below = m & ((1ull << l) - 1ull);
      g_rank[base + l] = k + (int)__popcll(below);
      g_np[base + l] = below ? (base + 63 - (int)__builtin_clzll(below)) : last;
    }
    if (m) last = base + 63 - (int)__builtin_clzll(m);
    k += (int)__popcll(m);
  }
  if (l == 0) g_counts[n] = k;
}

// ---------------- weights fold + encode (one dispatch, HD+1+NN blocks) ----------------
__global__ void __launch_bounds__(256)
k_weights(const void* __restrict__ xa, const void* __restrict__ We,
          const void* __restrict__ be, const void* __restrict__ Wq,
          const void* __restrict__ Wk, const void* __restrict__ Wr,
          const void* __restrict__ bq, const void* __restrict__ bk) {
  const int b = blockIdx.x, t = threadIdx.x;
  const int bf = g_dtype;
  const int wave = t >> 6, lane = t & 63;
  __shared__ float sw[HD];
  __shared__ float sr[4];
  if (b < HD) {
    sw[t] = ldin(Wq, b * HD + t, bf);               // Wq row b
    __syncthreads();
    float a0 = 0.f, a1 = 0.f, a2 = 0.f, a3 = 0.f;   // WQK[b][t] = Wq row b . Wk row t
    for (int h = 0; h < HD; h += 4) {
      a0 += sw[h]     * ldin(Wk, t * HD + h,     bf);
      a1 += sw[h + 1] * ldin(Wk, t * HD + h + 1, bf);
      a2 += sw[h + 2] * ldin(Wk, t * HD + h + 2, bf);
      a3 += sw[h + 3] * ldin(Wk, t * HD + h + 3, bf);
    }
    g_WQK[b * HD + t] = (a0 + a1) + (a2 + a3);
    float s = 0.f;
#pragma unroll
    for (int q = 0; q < 4; ++q) s += ldin(Wr, (q * HD + b) * HD + t, bf);
    g_WrS[b * HD + t] = s;
    float pv = sw[t] * ldin(bk, t, bf);             // vq[b] = Wq row b . bk
#pragma unroll
    for (int off = 32; off > 0; off >>= 1) pv += __shfl_down(pv, off, 64);
    if (lane == 0) sr[wave] = pv;
    __syncthreads();
    if (t == 0) g_vq[b] = sr[0] + sr[1] + sr[2] + sr[3];
  } else if (b == HD) {
    float a = 0.f;                                  // ck[t] = Wk row t . bq
    for (int h = 0; h < HD; ++h) a += ldin(Wk, t * HD + h, bf) * ldin(bq, h, bf);
    g_ck[t] = a;
    float pb = ldin(bq, t, bf) * ldin(bk, t, bf);
#pragma unroll
    for (int off = 32; off > 0; off >>= 1) pb += __shfl_down(pb, off, 64);
    if (lane == 0) sr[wave] = pb;
    __syncthreads();
    if (t == 0) g_bqk = sr[0] + sr[1] + sr[2] + sr[3];
  } else {                                          // encode node n
    const int n = b - HD - 1;
    if (t < FD) sw[t] = ldin(xa, n * FD + t, bf);
    __syncthreads();
    float acc = ldin(be, t, bf);
    for (int f = 0; f < FD; ++f) acc += sw[f] * ldin(We, f * HD + t, bf);
    g_hist[(size_t)(n * HIST) * HD + t] = acc;
  }
}

// ---------------- one attention step (256 threads cooperate) ----------------
__device__ __forceinline__ void step_body(
    int e, int S, int t, int bf,
    float* s_msg, float (*s_feats)[HD], float* s_vals, float* s_ns,
    float (*s_red)[HIST + 1], float* s_sc,
    const void* fmsg, const void* br_, const void* Wm, const void* bm) {
  const int n = g_node[e];
  const int k = g_rank[e];
  const int p = (e >= S) ? ((e - S) >> 3) : 0;
  const bool hc = (S + 8 * e) < TOTAL;
  const int c = k + 1;
  const int v = (c < HIST) ? c : HIST;
  const int slot = c % HIST;
  const int wave = t >> 6, lane = t & 63;

  s_msg[t] = (e < S) ? ldin(fmsg, e * MD + t, bf) : finz(g_msgb[(size_t)p * MD + t]);
#pragma unroll
  for (int j = 0; j < HIST; ++j)
    s_feats[j][t] = (j < v) ? finz(g_hist[(size_t)(n * HIST + j) * HD + t]) : 0.f;
  __syncthreads();

  // kq[t] = Wk row t . query == msg . WQK[:,t] + ck[t]   (4-acc unroll: short dep chain)
  float a0 = 0.f, a1 = 0.f, a2 = 0.f, a3 = 0.f;
  for (int m = 0; m < MD; m += 4) {
    a0 += s_msg[m]     * g_WQK[(m)     * HD + t];
    a1 += s_msg[m + 1] * g_WQK[(m + 1) * HD + t];
    a2 += s_msg[m + 2] * g_WQK[(m + 2) * HD + t];
    a3 += s_msg[m + 3] * g_WQK[(m + 3) * HD + t];
  }
  const float kq = g_ck[t] + ((a0 + a1) + (a2 + a3));

  float part[HIST + 1];
#pragma unroll
  for (int j = 0; j < HIST; ++j) part[j] = s_feats[j][t] * kq;
  part[HIST] = s_msg[t] * g_vq[t];
#pragma unroll
  for (int off = 32; off > 0; off >>= 1) {
#pragma unroll
    for (int j = 0; j <= HIST; ++j) part[j] += __shfl_down(part[j], off, 64);
  }
  if (lane == 0) {
#pragma unroll
    for (int j = 0; j <= HIST; ++j) s_red[wave][j] = part[j];
  }
  __syncthreads();
  if (t <= HIST) s_sc[t] = s_red[0][t] + s_red[1][t] + s_red[2][t] + s_red[3][t];
  __syncthreads();

  const float bkq = s_sc[HIST] + g_bqk;
  float lg[HIST];
#pragma unroll
  for (int j = 0; j < HIST; ++j)
    lg[j] = (j < v) ? ((s_sc[j] + bkq) * INV_SQRT_H) : -1e30f;
  float mx = lg[0];
#pragma unroll
  for (int j = 1; j < HIST; ++j) mx = fmaxf(mx, lg[j]);
  float e_[HIST], den = 0.f;
#pragma unroll
  for (int j = 0; j < HIST; ++j) { e_[j] = __expf(lg[j] - mx); den += e_[j]; }
  const float iden = 1.0f / den;
  float val = 0.f;
#pragma unroll
  for (int j = 0; j < HIST; ++j) val += e_[j] * s_feats[j][t];
  s_vals[t] = val * iden;
  __syncthreads();

  float b0 = 0.f, b1 = 0.f, b2 = 0.f, b3 = 0.f;     // newstate = vals @ WrS + br
  for (int h = 0; h < HD; h += 4) {
    b0 += s_vals[h]     * g_WrS[(h)     * HD + t];
    b1 += s_vals[h + 1] * g_WrS[(h + 1) * HD + t];
    b2 += s_vals[h + 2] * g_WrS[(h + 2) * HD + t];
    b3 += s_vals[h + 3] * g_WrS[(h + 3) * HD + t];
  }
  const float ns = ldin(br_, t, bf) + ((b0 + b1) + (b2 + b3));
  g_hist[(size_t)(n * HIST + slot) * HD + t] = ns;
  if (hc) s_ns[t] = ns;
  __syncthreads();

  if (hc) {
    float c0 = 0.f, c1 = 0.f, c2 = 0.f, c3 = 0.f;
    if (bf) {
      const bf16* w = (const bf16*)Wm;
      for (int h = 0; h < HD; h += 4) {
        c0 += s_ns[h]     * __bfloat162float(w[(h)     * MD + t]);
        c1 += s_ns[h + 1] * __bfloat162float(w[(h + 1) * MD + t]);
        c2 += s_ns[h + 2] * __bfloat162float(w[(h + 2) * MD + t]);
        c3 += s_ns[h + 3] * __bfloat162float(w[(h + 3) * MD + t]);
      }
      for (int m = 0; m < MD; m += 4) {
        c0 += s_msg[m]     * __bfloat162float(w[(HD + m)     * MD + t]);
        c1 += s_msg[m + 1] * __bfloat162float(w[(HD + m + 1) * MD + t]);
        c2 += s_msg[m + 2] * __bfloat162float(w[(HD + m + 2) * MD + t]);
        c3 += s_msg[m + 3] * __bfloat162float(w[(HD + m + 3) * MD + t]);
      }
    } else {
      const float* w = (const float*)Wm;
      for (int h = 0; h < HD; h += 4) {
        c0 += s_ns[h]     * w[(h)     * MD + t];
        c1 += s_ns[h + 1] * w[(h + 1) * MD + t];
        c2 += s_ns[h + 2] * w[(h + 2) * MD + t];
        c3 += s_ns[h + 3] * w[(h + 3) * MD + t];
      }
      for (int m = 0; m < MD; m += 4) {
        c0 += s_msg[m]     * w[(HD + m)     * MD + t];
        c1 += s_msg[m + 1] * w[(HD + m + 1) * MD + t];
        c2 += s_msg[m + 2] * w[(HD + m + 2) * MD + t];
        c3 += s_msg[m + 3] * w[(HD + m + 3) * MD + t];
      }
    }
    g_msgb[(size_t)e * MD + t] = ldin(bm, t, bf) + ((c0 + c1) + (c2 + c3));
  }
  __syncthreads();   // LDS reuse guard
}

// ---------------- dataflow executor: persistent blocks, per-entry done flags --------
// Block b owns entries b, b+G, b+2G, ... (ascending). Deps of entry e are strictly
// smaller indices (prev same-node occurrence, parent (e-S)>>3), so with all blocks
// co-resident the smallest unfinished entry always has its deps done -> progress.
// Co-residency: G=512 blocks, __launch_bounds__(256,2) => capacity 2 blocks/CU = 512;
// LDS 13.3 KB/block (limit ~11), waves 4/block (limit 8). A block is only withheld
// if ALL capacity is consumed, which requires all 512 placed.
#define FLOWG 512
__global__ void __launch_bounds__(256, 2)
k_flow(const void* __restrict__ fmsg, const void* __restrict__ br_,
       const void* __restrict__ Wm, const void* __restrict__ bm,
       const int* __restrict__ dS) {
  const int t = threadIdx.x;
  const int S = decode_S(dS);
  const int bf = g_dtype;
  __shared__ float s_msg[MD];
  __shared__ float s_feats[HIST][HD];
  __shared__ float s_vals[HD];
  __shared__ float s_ns[HD];
  __shared__ float s_red[4][HIST + 1];
  __shared__ float s_sc[HIST + 1];
  for (int e = (int)blockIdx.x; e < TOTAL; e += FLOWG) {
    if (t == 0) {
      const int prev = g_np[e];
      if (prev >= 0)
        while (!__hip_atomic_load(&g_done[prev], __ATOMIC_RELAXED,
                                  __HIP_MEMORY_SCOPE_AGENT))
          __builtin_amdgcn_s_sleep(2);
      if (e >= S) {
        const int p = (e - S) >> 3;
        while (!__hip_atomic_load(&g_done[p], __ATOMIC_RELAXED,
                                  __HIP_MEMORY_SCOPE_AGENT))
          __builtin_amdgcn_s_sleep(2);
      }
      __threadfence();           // acquire: invalidate this CU's caches -> fresh reads
    }
    __syncthreads();             // whole block sees published data
    step_body(e, S, t, bf, s_msg, s_feats, s_vals, s_ns, s_red, s_sc,
              fmsg, br_, Wm, bm);
    __threadfence();             // release part 1: every thread flushes its own stores
    __syncthreads();             // release part 2: all threads' stores globally visible
    if (t == 0)
      __hip_atomic_store(&g_done[e], 1, __ATOMIC_RELAXED,
                         __HIP_MEMORY_SCOPE_AGENT);
  }
}

// ---------------- final projection + log_softmax ----------------
__global__ void k_out(const void* __restrict__ Wd, const void* __restrict__ bd,
                      void* __restrict__ out) {
  __shared__ float sf[HD];
  const int b = blockIdx.x;
  const int pp = b >> 9;
  const int n = b & 511;
  const int t = threadIdx.x;                 // 0..63 == O dim
  const int bf = g_dtype;
  int occ = g_counts[n];
  if (occ < 0 || occ > TOTAL) occ = 0;
  const int slot = occ % HIST;               // (count-1)%HIST, count = 1+occ
  for (int h = t; h < HD; h += OD) sf[h] = finz(g_hist[(size_t)(n * HIST + slot) * HD + h]);
  __syncthreads();
  float acc = finz(ldin(bd, pp * OD + t, bf));
  for (int h = 0; h < HD; ++h) acc += sf[h] * ldin(Wd, (pp * HD + h) * OD + t, bf);
  acc = finz(acc);
  float mx = acc;
#pragma unroll
  for (int off = 32; off > 0; off >>= 1) mx = fmaxf(mx, __shfl_xor(mx, off, 64));
  float ex = __expf(acc - mx);
  float s = ex;
#pragma unroll
  for (int off = 32; off > 0; off >>= 1) s += __shfl_xor(s, off, 64);
  float r = finz(acc - mx - logf(s));
  const int oi = (pp * NN + n) * OD + t;
  if (bf) ((bf16*)out)[oi] = __float2bfloat16(r);
  else    ((float*)out)[oi] = r;
}

extern "C" void kernel_launch(void* const* d_in, const int* in_sizes, int n_in,
                              void* d_out, int out_size, void* d_ws, size_t ws_size,
                              hipStream_t stream) {
  const void* xa   = d_in[0];
  const int*  nbrs = (const int*)d_in[1];
  const void* fmsg = d_in[2];
  const void* We   = d_in[3];
  const void* be   = d_in[4];
  const void* Wq   = d_in[5];
  const void* bq   = d_in[6];
  const void* Wk   = d_in[7];
  const void* bk   = d_in[8];
  const void* Wr   = d_in[9];
  const void* br   = d_in[10];
  const void* Wm   = d_in[11];
  const void* bm   = d_in[12];
  const void* Wd   = d_in[13];
  const void* bd   = d_in[14];
  const int*  dS   = (const int*)d_in[15];
  (void)d_ws; (void)ws_size; (void)in_sizes; (void)n_in; (void)out_size;

  k_bfs<<<dim3(1), dim3(1024), 0, stream>>>((const unsigned*)xa, nbrs, dS);
  k_rank<<<dim3(NN), dim3(64), 0, stream>>>();
  k_weights<<<dim3(HD + 1 + NN), dim3(256), 0, stream>>>(xa, We, be, Wq, Wk, Wr, bq, bk);
  k_flow<<<dim3(FLOWG), dim3(256), 0, stream>>>(fmsg, br, Wm, bm, dS);
  k_out<<<dim3(PD * NN), dim3(OD), 0, stream>>>(Wd, bd, d_out);
}